// Round 18
// baseline (213.824 us; speedup 1.0000x reference)
//
#include <hip/hip_runtime.h>

#define NB_USERS 100000
#define NB_MOVIES 20000
#define KDIM 64
#define NPTS 2000000
#define RQ_LEVELS 8192            // rating quantization; table rows = RQ_LEVELS+1
#define UPB 128                   // users per bucket
#define NBUCK 782                 // ceil(NB_USERS / 128)
#define CHUNK 8192                // points per binA block (long write runs)
#define NCHUNK ((NPTS + CHUNK - 1) / CHUNK)
#define BCAP 3584                 // fused-kernel LDS capacity (mean 2560, sigma ~51 -> 20 sigma)
#define LOG2E 1.44269504088896f

#define MF_N (NB_MOVIES * KDIM)
#define RT_N ((RQ_LEVELS + 1) * KDIM)

typedef _Float16 f16x8 __attribute__((ext_vector_type(8)));
typedef float    f32x4 __attribute__((ext_vector_type(4)));

__device__ __forceinline__ float sigmoidf(float z) {
    return 1.0f / (1.0f + __expf(-z));
}
// w = -log2(e) * z  ->  sigmoid(z) = rcp(1 + 2^w)
__device__ __forceinline__ float sigmoid_w(float w) {
    return __builtin_amdgcn_rcpf(1.0f + __builtin_amdgcn_exp2f(w));
}

// ---------------- fused prep: mf16, rtab16, wcfrag ----------------
__global__ __launch_bounds__(256) void prep_kernel(
    const float* __restrict__ mf, const float* __restrict__ W_r,
    const float* __restrict__ b_r, const float* __restrict__ W_c,
    _Float16* __restrict__ mf16, _Float16* __restrict__ rtab16,
    _Float16* __restrict__ wcfrag)
{
    const int idx = blockIdx.x * 256 + threadIdx.x;
    if (idx < MF_N) {
        mf16[idx] = (_Float16)mf[idx];
    } else if (idx < MF_N + RT_N) {
        const int i = idx - MF_N;
        const int q = i >> 6, k = i & 63;
        rtab16[i] = (_Float16)sigmoidf(fmaf((float)q * (1.0f / RQ_LEVELS), W_r[k], b_r[k]));
    } else if (idx < MF_N + RT_N + 512) {
        const int i = idx - MF_N - RT_N;       // [0,512)
        const int ntkt = i >> 6;
        const int nt = ntkt >> 1, kt = ntkt & 1;
        const int lane = i & 63;
        const float* src = &W_c[(nt * 16 + (lane & 15)) * KDIM + kt * 32 + (lane >> 4) * 8];
        _Float16* dst = wcfrag + (size_t)ntkt * 512 + lane * 8;
        #pragma unroll
        for (int e = 0; e < 8; ++e) dst[e] = (_Float16)(src[e] * -LOG2E);
    }
}

// ---------------- bucket histogram (782 buckets of 128 users), 1024 threads ----------------
__global__ __launch_bounds__(1024) void bucket_hist_kernel(
    const int* __restrict__ du, int* __restrict__ bhist)
{
    __shared__ int h[NBUCK];
    for (int b = threadIdx.x; b < NBUCK; b += 1024) h[b] = 0;
    __syncthreads();
    int i = blockIdx.x * 1024 + threadIdx.x;
    const int stride = gridDim.x * 1024;
    for (; i < NPTS; i += stride) atomicAdd(&h[du[i] >> 7], 1);
    __syncthreads();
    for (int b = threadIdx.x; b < NBUCK; b += 1024)
        if (h[b]) atomicAdd(&bhist[b], h[b]);
}

// ---------------- bucket scan (1 block, 4 consecutive per thread) ----------------
__global__ __launch_bounds__(256) void bscan_kernel(
    const int* __restrict__ bhist, int* __restrict__ bstart, int* __restrict__ bcursor)
{
    __shared__ int scn[256];
    const int t = threadIdx.x;
    int c[4];
    int s = 0;
    #pragma unroll
    for (int j = 0; j < 4; ++j) {
        const int idx = t * 4 + j;
        c[j] = (idx < NBUCK) ? bhist[idx] : 0;
        s += c[j];
    }
    scn[t] = s;
    __syncthreads();
    for (int d = 1; d < 256; d <<= 1) {
        const int a = (t >= d) ? scn[t - d] : 0;
        __syncthreads();
        scn[t] += a;
        __syncthreads();
    }
    int run = scn[t] - s;
    #pragma unroll
    for (int j = 0; j < 4; ++j) {
        const int idx = t * 4 + j;
        if (idx < NBUCK) { bstart[idx] = run; bcursor[idx] = run; }
        run += c[j];
    }
}

// ---------------- binA: 1024 threads, READ-TWICE + big chunk ----------------
// word: x = (u<<15)|m  (u 17 bits, m 15 bits), y = rq. bucket = u>>7 = x>>22
__global__ __launch_bounds__(1024, 2) void binA_kernel(
    const int* __restrict__ du, const int* __restrict__ dm,
    const float* __restrict__ dr,
    int* __restrict__ bcursor, uint2* __restrict__ binned)
{
    __shared__ uint2 buf[CHUNK];          // 64 KB
    __shared__ int cnt[NBUCK];
    __shared__ int scn[1024];
    __shared__ int sbase[NBUCK];
    __shared__ int cur[NBUCK];
    __shared__ int gbase[NBUCK];

    const int t  = threadIdx.x;
    const int c0 = blockIdx.x * CHUNK;
    const int n  = min(CHUNK, NPTS - c0);

    for (int b = t; b < NBUCK; b += 1024) cnt[b] = 0;
    __syncthreads();

    // pass 1: count (reads du only; L2-hot for pass 2)
    for (int i = t; i < n; i += 1024)
        atomicAdd(&cnt[(unsigned)du[c0 + i] >> 7], 1);
    __syncthreads();

    // exclusive scan: 1 bucket per thread (NBUCK <= 1024), HS over 1024
    const int cv = (t < NBUCK) ? cnt[t] : 0;
    scn[t] = cv;
    __syncthreads();
    for (int d = 1; d < 1024; d <<= 1) {
        const int a = (t >= d) ? scn[t - d] : 0;
        __syncthreads();
        scn[t] += a;
        __syncthreads();
    }
    if (t < NBUCK) {
        const int e = scn[t] - cv;
        sbase[t] = e;
        cur[t]   = e;
        if (cv > 0) gbase[t] = atomicAdd(&bcursor[t], cv);
    }
    __syncthreads();

    // pass 2: re-read, pack, place grouped into LDS
    for (int i = t; i < n; i += 1024) {
        const unsigned u  = (unsigned)du[c0 + i];
        const unsigned m  = (unsigned)dm[c0 + i];
        const unsigned rq = (unsigned)(int)fmaf(dr[c0 + i], (float)RQ_LEVELS / 5.0f, 0.5f);
        const int pos = atomicAdd(&cur[u >> 7], 1);
        buf[pos] = make_uint2((u << 15) | m, rq);
    }
    __syncthreads();

    // grouped write to global (runs of ~10.5 points per bucket)
    for (int i = t; i < n; i += 1024) {
        const uint2 q = buf[i];
        const int b = q.x >> 22;
        binned[gbase[b] + (i - sbase[b])] = q;
    }
}

// ---------------- rbm_saved: rows n < 20000 from the UNSORTED stream ----------------
__global__ __launch_bounds__(256) void rbm_saved_kernel(
    const int* __restrict__ dm, const float* __restrict__ dr,
    const _Float16* __restrict__ mf16, const _Float16* __restrict__ rtab16,
    const _Float16* __restrict__ wcfrag, const float* __restrict__ b_c,
    float* __restrict__ rbm_saved)
{
    __shared__ _Float16 bsh[8 * 512];
    for (int i = threadIdx.x; i < 512; i += 256)
        ((f16x8*)bsh)[i] = ((const f16x8*)wcfrag)[i];
    __syncthreads();

    const int lane = threadIdx.x & 63;
    const int wave = blockIdx.x * (blockDim.x >> 6) + (threadIdx.x >> 6);
    const int NT = (NB_MOVIES + 63) / 64;      // 313
    if (wave >= NT) return;

    float wbcv[4];
    #pragma unroll
    for (int nt = 0; nt < 4; ++nt) wbcv[nt] = -LOG2E * b_c[nt * 16 + (lane & 15)];

    const int base = wave * 64;
    const int koff = (lane >> 4) * 8;

    #pragma unroll 1
    for (int mt = 0; mt < 4; ++mt) {
        const int pg = base + mt * 16 + (lane & 15);
        int   m = 0;
        float r = 0.f;
        if (pg < NB_MOVIES) { m = dm[pg]; r = dr[pg]; }
        const int rq = (int)fmaf(r, (float)RQ_LEVELS / 5.0f, 0.5f);

        const f16x8 ma = *(const f16x8*)(mf16   + (size_t)m  * KDIM + koff);
        const f16x8 mb = *(const f16x8*)(mf16   + (size_t)m  * KDIM + 32 + koff);
        const f16x8 ta = *(const f16x8*)(rtab16 + (size_t)rq * KDIM + koff);
        const f16x8 tb = *(const f16x8*)(rtab16 + (size_t)rq * KDIM + 32 + koff);
        const f16x8 a0 = ma * ta;
        const f16x8 a1 = mb * tb;

        f32x4 acc[4];
        #pragma unroll
        for (int nt = 0; nt < 4; ++nt) {
            const f16x8 b0 = *(const f16x8*)(bsh + (nt * 2 + 0) * 512 + lane * 8);
            const f16x8 b1 = *(const f16x8*)(bsh + (nt * 2 + 1) * 512 + lane * 8);
            acc[nt] = (f32x4){0.f, 0.f, 0.f, 0.f};
            acc[nt] = __builtin_amdgcn_mfma_f32_16x16x32_f16(a0, b0, acc[nt], 0, 0, 0);
            acc[nt] = __builtin_amdgcn_mfma_f32_16x16x32_f16(a1, b1, acc[nt], 0, 0, 0);
        }

        #pragma unroll
        for (int reg = 0; reg < 4; ++reg) {
            const int prow_g = base + mt * 16 + (lane >> 4) * 4 + reg;
            if (prow_g < NB_MOVIES) {
                #pragma unroll
                for (int nt = 0; nt < 4; ++nt) {
                    const float rbm = sigmoid_w(acc[nt][reg] + wbcv[nt]);
                    rbm_saved[(size_t)prow_g * KDIM + nt * 16 + (lane & 15)] = rbm;
                }
            }
        }
    }
}

// ---------------- phase 1 FUSED: in-LDS sort + MFMA + segmented reduce into LDS tile ----------------
// Block owns users [b*128, b*128+128): segment adds go to rbu_loc (LDS
// f32 atomics, no vmcnt exposure), then ONE coalesced flush writes rbu --
// which also replaces zeroing (every row is written).
__global__ __launch_bounds__(512, 4) void phase1_fused_kernel(
    const uint2* __restrict__ binned,
    const int* __restrict__ bhist, const int* __restrict__ bstart,
    const _Float16* __restrict__ mf16,
    const _Float16* __restrict__ rtab16,
    const _Float16* __restrict__ wcfrag,
    const float* __restrict__ b_c,
    float* __restrict__ rbu, float* __restrict__ nbrf)
{
    __shared__ uint2 buf[BCAP];           // 28.7 KB
    __shared__ _Float16 bsh[8 * 512];     // 8 KB
    __shared__ float rbu_loc[UPB * 65];   // 33.3 KB (stride 65: row access 2/bank = free)
    __shared__ int cnt[UPB];
    __shared__ int cur[UPB];

    const int t    = threadIdx.x;
    const int lane = t & 63;
    const int wid  = t >> 6;              // [0,8)
    const int g    = lane >> 4;
    const int b    = blockIdx.x;
    const int n    = bhist[b];
    const int s0   = bstart[b];

    if (t < 512) ((f16x8*)bsh)[t] = ((const f16x8*)wcfrag)[t];
    if (t < UPB) cnt[t] = 0;
    for (int i = t; i < UPB * 65; i += 512) rbu_loc[i] = 0.f;
    __syncthreads();

    // --- in-LDS counting sort by local user ---
    for (int i = t; i < n; i += 512)
        atomicAdd(&cnt[(binned[s0 + i].x >> 15) & (UPB - 1)], 1);
    __syncthreads();

    const int uid = b * UPB + t;
    if (t < UPB && uid < NB_USERS) nbrf[uid] = (float)cnt[t];

    const int inc = (t < UPB) ? cnt[t] : 0;
    if (t < UPB) cur[t] = inc;
    __syncthreads();
    for (int d = 1; d < UPB; d <<= 1) {
        const int a = (t < UPB && t >= d) ? cur[t - d] : 0;
        __syncthreads();
        if (t < UPB) cur[t] += a;
        __syncthreads();
    }
    if (t < UPB) cur[t] -= inc;           // exclusive
    __syncthreads();

    for (int i = t; i < n; i += 512) {
        const uint2 q  = binned[s0 + i];
        const int  lu  = (q.x >> 15) & (UPB - 1);
        const int  pos = atomicAdd(&cur[lu], 1);
        buf[pos] = q;
    }
    __syncthreads();

    float wbcv[4];
    #pragma unroll
    for (int nt = 0; nt < 4; ++nt) wbcv[nt] = -LOG2E * b_c[nt * 16 + (lane & 15)];
    const int koff = g * 8;

    const int T = (n + 63) >> 6;
    for (int tt = wid; tt < T; tt += 8) {
        const int t0 = tt * 64;

        // ---- Phase A: load all 4 quadrants' fragments (16 gathers in flight) ----
        f16x8 A0[4], A1[4];
        int   uats[4];
        #pragma unroll
        for (int mt = 0; mt < 4; ++mt) {
            const int pi = t0 + mt * 16 + (lane & 15);
            const uint2 ur = (pi < n) ? buf[pi] : make_uint2(0xFFFFFFFFu, 0u);
            uats[mt] = (int)(ur.x >> 15);          // sentinel 0x1FFFF for pad
            const int m  = min((int)(ur.x & 0x7fffu), NB_MOVIES - 1);
            const int rq = (int)ur.y;

            const f16x8 ma = *(const f16x8*)(mf16   + (size_t)m  * KDIM + koff);
            const f16x8 mb = *(const f16x8*)(mf16   + (size_t)m  * KDIM + 32 + koff);
            const f16x8 ta = *(const f16x8*)(rtab16 + (size_t)rq * KDIM + koff);
            const f16x8 tb = *(const f16x8*)(rtab16 + (size_t)rq * KDIM + 32 + koff);
            A0[mt] = ma * ta;
            A1[mt] = mb * tb;
        }

        // ---- Phase B: FULLY UNROLLED -> static indices, fragments stay in VGPRs ----
        #pragma unroll
        for (int mt = 0; mt < 4; ++mt) {
            const unsigned u_at = (unsigned)uats[mt];

            f32x4 acc[4];
            #pragma unroll
            for (int nt = 0; nt < 4; ++nt) {
                const f16x8 b0 = *(const f16x8*)(bsh + (nt * 2 + 0) * 512 + lane * 8);
                const f16x8 b1 = *(const f16x8*)(bsh + (nt * 2 + 1) * 512 + lane * 8);
                acc[nt] = (f32x4){0.f, 0.f, 0.f, 0.f};
                acc[nt] = __builtin_amdgcn_mfma_f32_16x16x32_f16(A0[mt], b0, acc[nt], 0, 0, 0);
                acc[nt] = __builtin_amdgcn_mfma_f32_16x16x32_f16(A1[mt], b1, acc[nt], 0, 0, 0);
            }

            #pragma unroll
            for (int nt = 0; nt < 4; ++nt)
                #pragma unroll
                for (int reg = 0; reg < 4; ++reg)
                    acc[nt][reg] = sigmoid_w(acc[nt][reg] + wbcv[nt]);

            // boundary: within each 16-lane group, lane-1 holds the previous point
            const unsigned u_prev = (unsigned)__shfl(uats[mt], lane - 1, 64);
            const bool boundary = ((lane & 15) == 0) || (u_at != u_prev);
            unsigned long long bm = __ballot(boundary) & 0xFFFFull;

            while (bm) {
                const int s = __builtin_ctzll(bm);
                bm &= bm - 1;
                const int e = bm ? __builtin_ctzll(bm) : 16;
                const unsigned useg =
                    (unsigned)__builtin_amdgcn_readlane(uats[mt], s);
                if (useg >= (unsigned)NB_USERS) continue;   // pad segment

                const int lo = s - g * 4;
                const int hi = e - g * 4;
                float p0 = 0.f, p1 = 0.f, p2 = 0.f, p3 = 0.f;
                #pragma unroll
                for (int reg = 0; reg < 4; ++reg) {
                    const bool in = (reg >= lo) && (reg < hi);
                    p0 += in ? acc[0][reg] : 0.f;
                    p1 += in ? acc[1][reg] : 0.f;
                    p2 += in ? acc[2][reg] : 0.f;
                    p3 += in ? acc[3][reg] : 0.f;
                }
                p0 += __shfl_xor(p0, 16, 64); p0 += __shfl_xor(p0, 32, 64);
                p1 += __shfl_xor(p1, 16, 64); p1 += __shfl_xor(p1, 32, 64);
                p2 += __shfl_xor(p2, 16, 64); p2 += __shfl_xor(p2, 32, 64);
                p3 += __shfl_xor(p3, 16, 64); p3 += __shfl_xor(p3, 32, 64);

                const float v01 = (g & 1) ? p1 : p0;
                const float v23 = (g & 1) ? p3 : p2;
                const float val = (g & 2) ? v23 : v01;
                // block-exclusive user range -> LDS accumulation
                atomicAdd(&rbu_loc[(useg & (UPB - 1)) * 65 + lane], val);
            }
        }
    }
    __syncthreads();

    // single coalesced flush (replaces both zeroing and atomic global writes)
    for (int r = wid; r < UPB; r += 8) {
        const int user = b * UPB + r;
        if (user < NB_USERS)
            rbu[(size_t)user * KDIM + lane] = rbu_loc[r * 65 + lane];
    }
}

// ---------------- phase 2 ----------------
__global__ __launch_bounds__(256) void phase2_kernel(
    const int* __restrict__ x_users,
    const int* __restrict__ x_movies,
    const float* __restrict__ mf,
    const float* __restrict__ rbu,
    const float* __restrict__ nbrf,
    const float* __restrict__ rbm_saved,
    const float* __restrict__ w_out,
    const float* __restrict__ b_out,
    float* __restrict__ out)
{
    const int lane = threadIdx.x & 63;
    const int wave = blockIdx.x * (blockDim.x >> 6) + (threadIdx.x >> 6);
    if (wave >= NB_USERS) return;

    const int u  = x_users[wave];
    const int xm = x_movies[wave];

    const float nb = fmaxf(1.0f, nbrf[u] - 1.0f);
    const float uf = (rbu[(size_t)u * KDIM + lane] -
                      rbm_saved[(size_t)xm * KDIM + lane]) / nb;
    float p = mf[(size_t)xm * KDIM + lane] * uf;

    #pragma unroll
    for (int off = 32; off > 0; off >>= 1)
        p += __shfl_xor(p, off, 64);

    if (lane == 0)
        out[wave] = (p * (1.0f / 64.0f) * w_out[0] + b_out[0]) * 5.0f;
}

extern "C" void kernel_launch(void* const* d_in, const int* in_sizes, int n_in,
                              void* d_out, int out_size, void* d_ws, size_t ws_size,
                              hipStream_t stream) {
    const int*   x_users      = (const int*)  d_in[0];
    const int*   x_movies     = (const int*)  d_in[1];
    const int*   data_users   = (const int*)  d_in[2];
    const int*   data_movies  = (const int*)  d_in[3];
    const float* data_ratings = (const float*)d_in[4];
    const float* mf           = (const float*)d_in[5];
    const float* W_r          = (const float*)d_in[6];
    const float* b_r          = (const float*)d_in[7];
    const float* W_c          = (const float*)d_in[8];
    const float* b_c          = (const float*)d_in[9];
    const float* w_out        = (const float*)d_in[10];
    const float* b_out        = (const float*)d_in[11];
    float* out = (float*)d_out;

    // workspace (~50.7 MB, no aliasing):
    float*     rbu       = (float*)d_ws;                            // 6.4M f32
    float*     nbrf      = rbu + (size_t)NB_USERS * KDIM;           // 100K f32
    float*     rbm_saved = nbrf + NB_USERS;                         // 1.28M f32
    uint2*     binned    = (uint2*)(rbm_saved + (size_t)NB_MOVIES * KDIM); // 2M uint2
    _Float16*  mf16      = (_Float16*)(binned + NPTS);              // 1.28M f16
    _Float16*  rtab16    = mf16 + (size_t)MF_N;                     // 524K f16
    _Float16*  wcfrag    = rtab16 + (size_t)RT_N;                   // 4096 f16
    int*       bhist     = (int*)(wcfrag + 8 * 512);
    int*       bstart    = bhist + NBUCK;
    int*       bcursor   = bstart + NBUCK;

    hipMemsetAsync(bhist, 0, NBUCK * sizeof(int), stream);

    prep_kernel<<<(MF_N + RT_N + 512 + 255) / 256, 256, 0, stream>>>(
        mf, W_r, b_r, W_c, mf16, rtab16, wcfrag);

    bucket_hist_kernel<<<512, 1024, 0, stream>>>(data_users, bhist);
    bscan_kernel<<<1, 256, 0, stream>>>(bhist, bstart, bcursor);

    binA_kernel<<<NCHUNK, 1024, 0, stream>>>(
        data_users, data_movies, data_ratings, bcursor, binned);

    rbm_saved_kernel<<<79, 256, 0, stream>>>(
        data_movies, data_ratings, mf16, rtab16, wcfrag, b_c, rbm_saved);

    phase1_fused_kernel<<<NBUCK, 512, 0, stream>>>(
        binned, bhist, bstart, mf16, rtab16, wcfrag, b_c, rbu, nbrf);

    phase2_kernel<<<(NB_USERS * 64 + 255) / 256, 256, 0, stream>>>(
        x_users, x_movies, mf, rbu, nbrf, rbm_saved, w_out, b_out, out);
}

// Round 19
// 169.896 us; speedup vs baseline: 1.2586x; 1.2586x over previous
//
#include <hip/hip_runtime.h>

#define NB_USERS 100000
#define NB_MOVIES 20000
#define KDIM 64
#define NPTS 2000000
#define NTILES (NPTS / 64)
#define RQ_LEVELS 8192            // rating quantization; table rows = RQ_LEVELS+1
#define UPB 128                   // users per bucket
#define NBUCK 782                 // ceil(NB_USERS / 128)
#define CHUNK 8192                // points per binA block (long write runs)
#define NCHUNK ((NPTS + CHUNK - 1) / CHUNK)
#define BCAP 3584                 // binB LDS capacity (mean 2560, sigma ~51 -> 20 sigma)
#define LOG2E 1.44269504088896f

#define MF_N (NB_MOVIES * KDIM)
#define RT_N ((RQ_LEVELS + 1) * KDIM)

typedef _Float16 f16x8 __attribute__((ext_vector_type(8)));
typedef float    f32x4 __attribute__((ext_vector_type(4)));

__device__ __forceinline__ float sigmoidf(float z) {
    return 1.0f / (1.0f + __expf(-z));
}
// w = -log2(e) * z  ->  sigmoid(z) = rcp(1 + 2^w)
__device__ __forceinline__ float sigmoid_w(float w) {
    return __builtin_amdgcn_rcpf(1.0f + __builtin_amdgcn_exp2f(w));
}

// ---------------- fused prep: mf16, rtab16, wcfrag ----------------
__global__ __launch_bounds__(256) void prep_kernel(
    const float* __restrict__ mf, const float* __restrict__ W_r,
    const float* __restrict__ b_r, const float* __restrict__ W_c,
    _Float16* __restrict__ mf16, _Float16* __restrict__ rtab16,
    _Float16* __restrict__ wcfrag)
{
    const int idx = blockIdx.x * 256 + threadIdx.x;
    if (idx < MF_N) {
        mf16[idx] = (_Float16)mf[idx];
    } else if (idx < MF_N + RT_N) {
        const int i = idx - MF_N;
        const int q = i >> 6, k = i & 63;
        rtab16[i] = (_Float16)sigmoidf(fmaf((float)q * (1.0f / RQ_LEVELS), W_r[k], b_r[k]));
    } else if (idx < MF_N + RT_N + 512) {
        const int i = idx - MF_N - RT_N;       // [0,512)
        const int ntkt = i >> 6;
        const int nt = ntkt >> 1, kt = ntkt & 1;
        const int lane = i & 63;
        const float* src = &W_c[(nt * 16 + (lane & 15)) * KDIM + kt * 32 + (lane >> 4) * 8];
        _Float16* dst = wcfrag + (size_t)ntkt * 512 + lane * 8;
        #pragma unroll
        for (int e = 0; e < 8; ++e) dst[e] = (_Float16)(src[e] * -LOG2E);
    }
}

// ---------------- bucket histogram (782 buckets of 128 users), 1024 threads ----------------
__global__ __launch_bounds__(1024) void bucket_hist_kernel(
    const int* __restrict__ du, int* __restrict__ bhist)
{
    __shared__ int h[NBUCK];
    for (int b = threadIdx.x; b < NBUCK; b += 1024) h[b] = 0;
    __syncthreads();
    int i = blockIdx.x * 1024 + threadIdx.x;
    const int stride = gridDim.x * 1024;
    for (; i < NPTS; i += stride) atomicAdd(&h[du[i] >> 7], 1);
    __syncthreads();
    for (int b = threadIdx.x; b < NBUCK; b += 1024)
        if (h[b]) atomicAdd(&bhist[b], h[b]);
}

// ---------------- bucket scan (1 block, 4 consecutive per thread) ----------------
__global__ __launch_bounds__(256) void bscan_kernel(
    const int* __restrict__ bhist, int* __restrict__ bstart, int* __restrict__ bcursor)
{
    __shared__ int scn[256];
    const int t = threadIdx.x;
    int c[4];
    int s = 0;
    #pragma unroll
    for (int j = 0; j < 4; ++j) {
        const int idx = t * 4 + j;
        c[j] = (idx < NBUCK) ? bhist[idx] : 0;
        s += c[j];
    }
    scn[t] = s;
    __syncthreads();
    for (int d = 1; d < 256; d <<= 1) {
        const int a = (t >= d) ? scn[t - d] : 0;
        __syncthreads();
        scn[t] += a;
        __syncthreads();
    }
    int run = scn[t] - s;
    #pragma unroll
    for (int j = 0; j < 4; ++j) {
        const int idx = t * 4 + j;
        if (idx < NBUCK) { bstart[idx] = run; bcursor[idx] = run; }
        run += c[j];
    }
}

// ---------------- binA: 1024 threads, READ-TWICE + big chunk ----------------
// word: x = (u<<15)|m  (u 17 bits, m 15 bits), y = rq. bucket = u>>7 = x>>22
__global__ __launch_bounds__(1024, 2) void binA_kernel(
    const int* __restrict__ du, const int* __restrict__ dm,
    const float* __restrict__ dr,
    int* __restrict__ bcursor, uint2* __restrict__ binned)
{
    __shared__ uint2 buf[CHUNK];          // 64 KB
    __shared__ int cnt[NBUCK];
    __shared__ int scn[1024];
    __shared__ int sbase[NBUCK];
    __shared__ int cur[NBUCK];
    __shared__ int gbase[NBUCK];

    const int t  = threadIdx.x;
    const int c0 = blockIdx.x * CHUNK;
    const int n  = min(CHUNK, NPTS - c0);

    for (int b = t; b < NBUCK; b += 1024) cnt[b] = 0;
    __syncthreads();

    // pass 1: count (reads du only; L2-hot for pass 2)
    for (int i = t; i < n; i += 1024)
        atomicAdd(&cnt[(unsigned)du[c0 + i] >> 7], 1);
    __syncthreads();

    // exclusive scan: 1 bucket per thread (NBUCK <= 1024), HS over 1024
    const int cv = (t < NBUCK) ? cnt[t] : 0;
    scn[t] = cv;
    __syncthreads();
    for (int d = 1; d < 1024; d <<= 1) {
        const int a = (t >= d) ? scn[t - d] : 0;
        __syncthreads();
        scn[t] += a;
        __syncthreads();
    }
    if (t < NBUCK) {
        const int e = scn[t] - cv;
        sbase[t] = e;
        cur[t]   = e;
        if (cv > 0) gbase[t] = atomicAdd(&bcursor[t], cv);
    }
    __syncthreads();

    // pass 2: re-read, pack, place grouped into LDS
    for (int i = t; i < n; i += 1024) {
        const unsigned u  = (unsigned)du[c0 + i];
        const unsigned m  = (unsigned)dm[c0 + i];
        const unsigned rq = (unsigned)(int)fmaf(dr[c0 + i], (float)RQ_LEVELS / 5.0f, 0.5f);
        const int pos = atomicAdd(&cur[u >> 7], 1);
        buf[pos] = make_uint2((u << 15) | m, rq);
    }
    __syncthreads();

    // grouped write to global (runs of ~10.5 points per bucket)
    for (int i = t; i < n; i += 1024) {
        const uint2 q = buf[i];
        const int b = q.x >> 22;
        binned[gbase[b] + (i - sbase[b])] = q;
    }
}

// ---------------- binB: sort bucket by user in LDS, coalesced write + nbrf ----------------
__global__ __launch_bounds__(256) void binB_kernel(
    const uint2* __restrict__ binned,
    const int* __restrict__ bhist, const int* __restrict__ bstart,
    uint2* __restrict__ sorted, float* __restrict__ nbrf)
{
    __shared__ uint2 buf[BCAP];           // 28.7 KB
    __shared__ int cnt[UPB];
    __shared__ int cur[UPB];

    const int t  = threadIdx.x;
    const int b  = blockIdx.x;
    const int n  = bhist[b];
    const int s0 = bstart[b];

    if (t < UPB) cnt[t] = 0;
    __syncthreads();

    for (int i = t; i < n; i += 256)
        atomicAdd(&cnt[(binned[s0 + i].x >> 15) & (UPB - 1)], 1);
    __syncthreads();

    const int uid = b * UPB + t;
    if (t < UPB && uid < NB_USERS) nbrf[uid] = (float)cnt[t];

    const int inc = (t < UPB) ? cnt[t] : 0;
    if (t < UPB) cur[t] = inc;
    __syncthreads();
    for (int d = 1; d < UPB; d <<= 1) {
        const int a = (t < UPB && t >= d) ? cur[t - d] : 0;
        __syncthreads();
        if (t < UPB) cur[t] += a;
        __syncthreads();
    }
    if (t < UPB) cur[t] -= inc;           // exclusive
    __syncthreads();

    for (int i = t; i < n; i += 256) {
        const uint2 q  = binned[s0 + i];
        const int  lu  = (q.x >> 15) & (UPB - 1);
        const int  pos = atomicAdd(&cur[lu], 1);
        buf[pos] = q;
    }
    __syncthreads();

    for (int i = t; i < n; i += 256)
        sorted[s0 + i] = buf[i];
}

// ---------------- rbm_saved: rows n < 20000 from the UNSORTED stream ----------------
__global__ __launch_bounds__(256) void rbm_saved_kernel(
    const int* __restrict__ dm, const float* __restrict__ dr,
    const _Float16* __restrict__ mf16, const _Float16* __restrict__ rtab16,
    const _Float16* __restrict__ wcfrag, const float* __restrict__ b_c,
    float* __restrict__ rbm_saved)
{
    __shared__ _Float16 bsh[8 * 512];
    for (int i = threadIdx.x; i < 512; i += 256)
        ((f16x8*)bsh)[i] = ((const f16x8*)wcfrag)[i];
    __syncthreads();

    const int lane = threadIdx.x & 63;
    const int wave = blockIdx.x * (blockDim.x >> 6) + (threadIdx.x >> 6);
    const int NT = (NB_MOVIES + 63) / 64;      // 313
    if (wave >= NT) return;

    float wbcv[4];
    #pragma unroll
    for (int nt = 0; nt < 4; ++nt) wbcv[nt] = -LOG2E * b_c[nt * 16 + (lane & 15)];

    const int base = wave * 64;
    const int koff = (lane >> 4) * 8;

    #pragma unroll 1
    for (int mt = 0; mt < 4; ++mt) {
        const int pg = base + mt * 16 + (lane & 15);
        int   m = 0;
        float r = 0.f;
        if (pg < NB_MOVIES) { m = dm[pg]; r = dr[pg]; }
        const int rq = (int)fmaf(r, (float)RQ_LEVELS / 5.0f, 0.5f);

        const f16x8 ma = *(const f16x8*)(mf16   + (size_t)m  * KDIM + koff);
        const f16x8 mb = *(const f16x8*)(mf16   + (size_t)m  * KDIM + 32 + koff);
        const f16x8 ta = *(const f16x8*)(rtab16 + (size_t)rq * KDIM + koff);
        const f16x8 tb = *(const f16x8*)(rtab16 + (size_t)rq * KDIM + 32 + koff);
        const f16x8 a0 = ma * ta;
        const f16x8 a1 = mb * tb;

        f32x4 acc[4];
        #pragma unroll
        for (int nt = 0; nt < 4; ++nt) {
            const f16x8 b0 = *(const f16x8*)(bsh + (nt * 2 + 0) * 512 + lane * 8);
            const f16x8 b1 = *(const f16x8*)(bsh + (nt * 2 + 1) * 512 + lane * 8);
            acc[nt] = (f32x4){0.f, 0.f, 0.f, 0.f};
            acc[nt] = __builtin_amdgcn_mfma_f32_16x16x32_f16(a0, b0, acc[nt], 0, 0, 0);
            acc[nt] = __builtin_amdgcn_mfma_f32_16x16x32_f16(a1, b1, acc[nt], 0, 0, 0);
        }

        #pragma unroll
        for (int reg = 0; reg < 4; ++reg) {
            const int prow_g = base + mt * 16 + (lane >> 4) * 4 + reg;
            if (prow_g < NB_MOVIES) {
                #pragma unroll
                for (int nt = 0; nt < 4; ++nt) {
                    const float rbm = sigmoid_w(acc[nt][reg] + wbcv[nt]);
                    rbm_saved[(size_t)prow_g * KDIM + nt * 16 + (lane & 15)] = rbm;
                }
            }
        }
    }
}

// ---------------- phase 1: user-sorted stream, grid-stride, segmented reduce (R9-verified) ----------------
__global__ __launch_bounds__(256, 4) void phase1_sorted_kernel(
    const uint2* __restrict__ sorted_ur,
    const _Float16* __restrict__ mf16,
    const _Float16* __restrict__ rtab16,
    const _Float16* __restrict__ wcfrag,
    const float* __restrict__ b_c,
    float* __restrict__ rbu)
{
    __shared__ _Float16 bsh[8 * 512];     // 8 KB
    for (int i = threadIdx.x; i < 512; i += 256)
        ((f16x8*)bsh)[i] = ((const f16x8*)wcfrag)[i];
    __syncthreads();

    const int lane = threadIdx.x & 63;
    const int wave = blockIdx.x * (blockDim.x >> 6) + (threadIdx.x >> 6);
    const int nwav = gridDim.x * (blockDim.x >> 6);

    float wbcv[4];
    #pragma unroll
    for (int nt = 0; nt < 4; ++nt) wbcv[nt] = -LOG2E * b_c[nt * 16 + (lane & 15)];

    const int koff = (lane >> 4) * 8;
    const int g    = lane >> 4;

    for (int it = wave; it < NTILES; it += nwav) {
        const int base = it * 64;

        #pragma unroll 1
        for (int mt = 0; mt < 4; ++mt) {
            const uint2 ur = sorted_ur[base + mt * 16 + (lane & 15)];
            const unsigned u_at = ur.x >> 15;
            const int      m    = (int)(ur.x & 0x7fffu);
            const int      rq   = (int)ur.y;

            const f16x8 ma = *(const f16x8*)(mf16   + (size_t)m  * KDIM + koff);
            const f16x8 mb = *(const f16x8*)(mf16   + (size_t)m  * KDIM + 32 + koff);
            const f16x8 ta = *(const f16x8*)(rtab16 + (size_t)rq * KDIM + koff);
            const f16x8 tb = *(const f16x8*)(rtab16 + (size_t)rq * KDIM + 32 + koff);
            const f16x8 a0 = ma * ta;     // v_pk_mul_f16
            const f16x8 a1 = mb * tb;

            f32x4 acc[4];
            #pragma unroll
            for (int nt = 0; nt < 4; ++nt) {
                const f16x8 b0 = *(const f16x8*)(bsh + (nt * 2 + 0) * 512 + lane * 8);
                const f16x8 b1 = *(const f16x8*)(bsh + (nt * 2 + 1) * 512 + lane * 8);
                acc[nt] = (f32x4){0.f, 0.f, 0.f, 0.f};
                acc[nt] = __builtin_amdgcn_mfma_f32_16x16x32_f16(a0, b0, acc[nt], 0, 0, 0);
                acc[nt] = __builtin_amdgcn_mfma_f32_16x16x32_f16(a1, b1, acc[nt], 0, 0, 0);
            }

            #pragma unroll
            for (int nt = 0; nt < 4; ++nt)
                #pragma unroll
                for (int reg = 0; reg < 4; ++reg)
                    acc[nt][reg] = sigmoid_w(acc[nt][reg] + wbcv[nt]);

            const unsigned u_prev =
                (unsigned)__shfl((int)u_at, lane - 1, 64);
            const bool boundary = ((lane & 15) == 0) || (u_at != u_prev);
            unsigned long long bm = __ballot(boundary) & 0xFFFFull;

            while (bm) {
                const int s = __builtin_ctzll(bm);
                bm &= bm - 1;
                const int e = bm ? __builtin_ctzll(bm) : 16;
                const unsigned useg =
                    (unsigned)__builtin_amdgcn_readlane((int)u_at, s);

                const int lo = s - g * 4;
                const int hi = e - g * 4;
                float p0 = 0.f, p1 = 0.f, p2 = 0.f, p3 = 0.f;
                #pragma unroll
                for (int reg = 0; reg < 4; ++reg) {
                    const bool in = (reg >= lo) && (reg < hi);
                    p0 += in ? acc[0][reg] : 0.f;
                    p1 += in ? acc[1][reg] : 0.f;
                    p2 += in ? acc[2][reg] : 0.f;
                    p3 += in ? acc[3][reg] : 0.f;
                }
                p0 += __shfl_xor(p0, 16, 64); p0 += __shfl_xor(p0, 32, 64);
                p1 += __shfl_xor(p1, 16, 64); p1 += __shfl_xor(p1, 32, 64);
                p2 += __shfl_xor(p2, 16, 64); p2 += __shfl_xor(p2, 32, 64);
                p3 += __shfl_xor(p3, 16, 64); p3 += __shfl_xor(p3, 32, 64);

                const float v01 = (g & 1) ? p1 : p0;
                const float v23 = (g & 1) ? p3 : p2;
                const float val = (g & 2) ? v23 : v01;
                atomicAdd(&rbu[(size_t)useg * KDIM + lane], val);
            }
        }
    }
}

// ---------------- phase 2 ----------------
__global__ __launch_bounds__(256) void phase2_kernel(
    const int* __restrict__ x_users,
    const int* __restrict__ x_movies,
    const float* __restrict__ mf,
    const float* __restrict__ rbu,
    const float* __restrict__ nbrf,
    const float* __restrict__ rbm_saved,
    const float* __restrict__ w_out,
    const float* __restrict__ b_out,
    float* __restrict__ out)
{
    const int lane = threadIdx.x & 63;
    const int wave = blockIdx.x * (blockDim.x >> 6) + (threadIdx.x >> 6);
    if (wave >= NB_USERS) return;

    const int u  = x_users[wave];
    const int xm = x_movies[wave];

    const float nb = fmaxf(1.0f, nbrf[u] - 1.0f);
    const float uf = (rbu[(size_t)u * KDIM + lane] -
                      rbm_saved[(size_t)xm * KDIM + lane]) / nb;
    float p = mf[(size_t)xm * KDIM + lane] * uf;

    #pragma unroll
    for (int off = 32; off > 0; off >>= 1)
        p += __shfl_xor(p, off, 64);

    if (lane == 0)
        out[wave] = (p * (1.0f / 64.0f) * w_out[0] + b_out[0]) * 5.0f;
}

extern "C" void kernel_launch(void* const* d_in, const int* in_sizes, int n_in,
                              void* d_out, int out_size, void* d_ws, size_t ws_size,
                              hipStream_t stream) {
    const int*   x_users      = (const int*)  d_in[0];
    const int*   x_movies     = (const int*)  d_in[1];
    const int*   data_users   = (const int*)  d_in[2];
    const int*   data_movies  = (const int*)  d_in[3];
    const float* data_ratings = (const float*)d_in[4];
    const float* mf           = (const float*)d_in[5];
    const float* W_r          = (const float*)d_in[6];
    const float* b_r          = (const float*)d_in[7];
    const float* W_c          = (const float*)d_in[8];
    const float* b_c          = (const float*)d_in[9];
    const float* w_out        = (const float*)d_in[10];
    const float* b_out        = (const float*)d_in[11];
    float* out = (float*)d_out;

    // workspace (~50.8 MB, R9-style aliasing):
    //   rbu 25.6 MB  [first 16 MB aliased as `binned` during sort]
    //   nbrf, rbm_saved, sorted_ur 16 MB, mf16, rtab16, wcfrag, bhist/bstart/bcursor
    float*     rbu       = (float*)d_ws;
    uint2*     binned    = (uint2*)d_ws;      // alias (consumed before rbu memset)
    float*     nbrf      = rbu + (size_t)NB_USERS * KDIM;
    float*     rbm_saved = nbrf + NB_USERS;
    uint2*     sorted_ur = (uint2*)(rbm_saved + (size_t)NB_MOVIES * KDIM);
    _Float16*  mf16      = (_Float16*)(sorted_ur + NPTS);
    _Float16*  rtab16    = mf16 + (size_t)MF_N;
    _Float16*  wcfrag    = rtab16 + (size_t)RT_N;
    int*       bhist     = (int*)(wcfrag + 8 * 512);
    int*       bstart    = bhist + NBUCK;
    int*       bcursor   = bstart + NBUCK;

    hipMemsetAsync(bhist, 0, NBUCK * sizeof(int), stream);

    prep_kernel<<<(MF_N + RT_N + 512 + 255) / 256, 256, 0, stream>>>(
        mf, W_r, b_r, W_c, mf16, rtab16, wcfrag);

    bucket_hist_kernel<<<512, 1024, 0, stream>>>(data_users, bhist);
    bscan_kernel<<<1, 256, 0, stream>>>(bhist, bstart, bcursor);

    binA_kernel<<<NCHUNK, 1024, 0, stream>>>(
        data_users, data_movies, data_ratings, bcursor, binned);

    rbm_saved_kernel<<<79, 256, 0, stream>>>(
        data_movies, data_ratings, mf16, rtab16, wcfrag, b_c, rbm_saved);

    binB_kernel<<<NBUCK, 256, 0, stream>>>(binned, bhist, bstart, sorted_ur, nbrf);

    // binned fully consumed -> safe to zero rbu (aliases it)
    hipMemsetAsync(rbu, 0, (size_t)NB_USERS * KDIM * sizeof(float), stream);

    phase1_sorted_kernel<<<2048, 256, 0, stream>>>(
        sorted_ur, mf16, rtab16, wcfrag, b_c, rbu);

    phase2_kernel<<<(NB_USERS * 64 + 255) / 256, 256, 0, stream>>>(
        x_users, x_movies, mf, rbu, nbrf, rbm_saved, w_out, b_out, out);
}